// Round 2
// baseline (302.819 us; speedup 1.0000x reference)
//
#include <hip/hip_runtime.h>

// RelativePosition: out[b, p(i,j)] = a[b,j] - a[b,i] for j > i, row-major
// over (i, j). B=128, N=1024, P = N*(N-1)/2 = 523776 pairs per batch.
// Write-bound: ~268 MB of fp32 stores per launch; input is 512 KB (L2-hot).

#define NPOS 1024
#define PAIRS ((NPOS * (NPOS - 1)) / 2)  // 523776, divisible by 4

__global__ __launch_bounds__(256) void relpos_kernel(const float* __restrict__ in,
                                                     float* __restrict__ out) {
    const int nRows = NPOS - 1;  // 1023 rows with >=1 element (i = 0..1022)
    const int bid = blockIdx.x;
    const int b = bid / nRows;
    const int i = bid - b * nRows;

    const float* __restrict__ a = in + b * NPOS;
    const float ai = a[i];

    // Flat output offset of this row. Max value ~67M: fits int32.
    const int rowStart = b * PAIRS + i * nRows - (i * (i - 1)) / 2;
    const int cnt = nRows - i;                 // elements in this row
    float* __restrict__ o = out + rowStart;
    const float* __restrict__ src = a + i + 1; // a[j] for j = i+1 ...

    const int tid = threadIdx.x;

    // Scalar head to reach float4 alignment of the store pointer.
    int head = (4 - (rowStart & 3)) & 3;
    if (head > cnt) head = cnt;
    if (tid < head) o[tid] = src[tid] - ai;

    // Vectorized main body: float4 stores (16 B/lane), scalar loads (L1/L2 hits).
    const int nvec = (cnt - head) >> 2;
    for (int v = tid; v < nvec; v += 256) {
        const int t = head + (v << 2);
        float4 r;
        r.x = src[t]     - ai;
        r.y = src[t + 1] - ai;
        r.z = src[t + 2] - ai;
        r.w = src[t + 3] - ai;
        *reinterpret_cast<float4*>(o + t) = r;
    }

    // Scalar tail.
    const int t2 = head + (nvec << 2) + tid;
    if (t2 < cnt) o[t2] = src[t2] - ai;
}

extern "C" void kernel_launch(void* const* d_in, const int* in_sizes, int n_in,
                              void* d_out, int out_size, void* d_ws, size_t ws_size,
                              hipStream_t stream) {
    const float* in = (const float*)d_in[0];
    float* out = (float*)d_out;
    const int B = in_sizes[0] / NPOS;  // 128
    const dim3 grid(B * (NPOS - 1));   // one block per (b, i) output row
    relpos_kernel<<<grid, 256, 0, stream>>>(in, out);
}

// Round 3
// 282.732 us; speedup vs baseline: 1.0710x; 1.0710x over previous
//
#include <hip/hip_runtime.h>
#include <math.h>

// RelativePosition: out[b, p(i,j)] = a[b,j] - a[b,i] for j > i, row-major over
// (i,j). B=128, N=1024, PAIRS = N*(N-1)/2 = 523776 per batch (268 MB fp32 out).
// Write-bound. Round-2 restructure: uniform flat-output chunks per block
// (old per-row blocks had <=1 float4/thread and huge imbalance -> 1.9 TB/s).

#define NPOS  1024
#define PAIRS 523776              // NPOS*(NPOS-1)/2
#define CHUNK 16368               // PAIRS / 32, divisible by 4
#define CHUNKS_PER_BATCH 32
#define F4_PER_CHUNK (CHUNK / 4)  // 4092

__device__ __forceinline__ int rowStartOf(int i) {
    // flat index where row i begins: i*(2N-1-i)/2
    return (i * (2 * NPOS - 1 - i)) >> 1;
}

__device__ __forceinline__ int row_of(int p) {
    // i such that rowStartOf(i) <= p < rowStartOf(i+1).
    // D = (2N-1)^2 - 8p is an exact fp32 integer (< 2^23) and a perfect
    // square exactly at row starts, so the estimate is exact there; the
    // fixup loops cover any half-ulp slop elsewhere (almost never taken).
    const float D = (float)(4190209 - 8 * p);  // (2047)^2 - 8p >= 9
    int i = (int)((2047.0f - sqrtf(D)) * 0.5f);
    if (i < 0) i = 0;
    if (i > NPOS - 2) i = NPOS - 2;
    while (rowStartOf(i + 1) <= p) ++i;
    while (rowStartOf(i) > p) --i;
    return i;
}

__global__ __launch_bounds__(256) void relpos_kernel(const float* __restrict__ in,
                                                     float* __restrict__ out) {
    const int b = blockIdx.x / CHUNKS_PER_BATCH;
    const int c = blockIdx.x - b * CHUNKS_PER_BATCH;

    const float* __restrict__ a = in + b * NPOS;     // 4 KB row, L1/L2-hot
    float* __restrict__ ob = out + b * PAIRS;
    const int chunkBase = c * CHUNK;                 // within-batch flat start

    for (int v = threadIdx.x; v < F4_PER_CHUNK; v += 256) {
        const int p = chunkBase + (v << 2);          // float4-aligned flat idx
        const int i = row_of(p);
        const int j = i + 1 + (p - rowStartOf(i));
        if (j + 3 <= NPOS - 1) {
            // Whole float4 inside row i (99%+ of iterations).
            const float ai = a[i];
            float4 r;
            r.x = a[j]     - ai;
            r.y = a[j + 1] - ai;
            r.z = a[j + 2] - ai;
            r.w = a[j + 3] - ai;
            *reinterpret_cast<float4*>(ob + p) = r;
        } else {
            // Row-boundary straddle: per-element (may span several short rows).
            #pragma unroll
            for (int e = 0; e < 4; ++e) {
                const int pe = p + e;
                const int ie = row_of(pe);
                const int je = ie + 1 + (pe - rowStartOf(ie));
                ob[pe] = a[je] - a[ie];
            }
        }
    }
}

extern "C" void kernel_launch(void* const* d_in, const int* in_sizes, int n_in,
                              void* d_out, int out_size, void* d_ws, size_t ws_size,
                              hipStream_t stream) {
    const float* in = (const float*)d_in[0];
    float* out = (float*)d_out;
    const int B = in_sizes[0] / NPOS;  // 128
    relpos_kernel<<<dim3(B * CHUNKS_PER_BATCH), 256, 0, stream>>>(in, out);
}